// Round 8
// baseline (1319.138 us; speedup 1.0000x reference)
//
#include <hip/hip_runtime.h>
#include <math.h>
#include <stdint.h>

#define EPS 1e-8f
#define FMAXV 3.402823466e38f

// ---------------- spatial grid parameters ----------------
#define GD 64
#define CELLS (GD * GD * GD)          // 262144 = 256 * 1024 exactly
#define BOX_LO (-6.0f)
#define CELL_SZ 0.1875f               // 12.0 / 64
#define INV_CELL (1.0f / 0.1875f)
#define MARGIN 2e-4f                  // >> max |score - true dist^2| (~4e-5)

__device__ __forceinline__ int cell_coord(float x) {
    int c = (int)floorf((x - BOX_LO) * INV_CELL);
    return min(max(c, 0), GD - 1);
}

// Monotone float->uint key (d >= tiny negative noise possible, full mapping):
__device__ __forceinline__ unsigned key_hi(float d) {
    unsigned b = __float_as_uint(d);
    return (b & 0x80000000u) ? ~b : (b | 0x80000000u);
}
__device__ __forceinline__ float key_d(unsigned long long k) {
    unsigned h = (unsigned)(k >> 32);
    unsigned b = (h & 0x80000000u) ? (h & 0x7fffffffu) : ~h;
    return __uint_as_float(b);
}
__device__ __forceinline__ unsigned long long shfl_xor_u64(unsigned long long v, int m) {
    int lo = __shfl_xor((int)(unsigned)(v & 0xffffffffu), m, 64);
    int hi = __shfl_xor((int)(unsigned)(v >> 32), m, 64);
    return ((unsigned long long)(unsigned)hi << 32) | (unsigned)lo;
}
// Branchless sorted top-3 insert on u64 keys. Strict '<' on (d_bits, j)
// = lexicographic (score, index) => exactly top_k's lowest-index tie-break.
__device__ __forceinline__ void insert3k(unsigned long long k,
        unsigned long long& k0, unsigned long long& k1, unsigned long long& k2) {
    const bool c0 = k < k0, c1 = k < k1, c2 = k < k2;
    k2 = c1 ? k1 : (c2 ? k : k2);
    k1 = c0 ? k0 : (c1 ? k : k1);
    k0 = c0 ? k : k0;
}

// ---------------- grid-build kernels ----------------
__global__ void k_hist(const float* __restrict__ sp, int* __restrict__ counts, int N) {
    int j = blockIdx.x * blockDim.x + threadIdx.x;
    if (j >= N) return;
    int cx = cell_coord(sp[3 * j]), cy = cell_coord(sp[3 * j + 1]), cz = cell_coord(sp[3 * j + 2]);
    atomicAdd(&counts[(cz * GD + cy) * GD + cx], 1);
}

__global__ __launch_bounds__(1024) void k_scanA(const int* __restrict__ counts,
        int* __restrict__ offs, int* __restrict__ bsum) {
    __shared__ int sh[1024];
    int i = blockIdx.x * 1024 + threadIdx.x;
    int v = counts[i];
    sh[threadIdx.x] = v;
    __syncthreads();
    for (int o = 1; o < 1024; o <<= 1) {
        int t = (threadIdx.x >= o) ? sh[threadIdx.x - o] : 0;
        __syncthreads();
        sh[threadIdx.x] += t;
        __syncthreads();
    }
    offs[i] = sh[threadIdx.x] - v;          // block-local exclusive
    if (threadIdx.x == 1023) bsum[blockIdx.x] = sh[1023];
}

__global__ __launch_bounds__(256) void k_scanB(const int* __restrict__ bsum, int* __restrict__ bbase) {
    __shared__ int sh[256];
    int v = bsum[threadIdx.x];
    sh[threadIdx.x] = v;
    __syncthreads();
    for (int o = 1; o < 256; o <<= 1) {
        int t = (threadIdx.x >= o) ? sh[threadIdx.x - o] : 0;
        __syncthreads();
        sh[threadIdx.x] += t;
        __syncthreads();
    }
    bbase[threadIdx.x] = sh[threadIdx.x] - v;
}

__global__ __launch_bounds__(1024) void k_scanC(int* __restrict__ offs, int* __restrict__ cursor,
        const int* __restrict__ bbase, int Ntot) {
    int i = blockIdx.x * 1024 + threadIdx.x;
    int o = offs[i] + bbase[blockIdx.x];
    offs[i] = o;
    cursor[i] = o;
    if (i == CELLS - 1) offs[CELLS] = Ntot;
}

// Scatter points into grid order; fold in the FROZEN preproc:
// spts[pos] = (-2x,-2y,-2z, s2), s2 = (x*x + y*y) + z*z strict no-FMA.
// (validated bit-exact in R5 — do not change)
__global__ void k_scatter(const float* __restrict__ sp, int* __restrict__ cursor,
        float4* __restrict__ spts, int* __restrict__ sidx, int N) {
    int j = blockIdx.x * blockDim.x + threadIdx.x;
    if (j >= N) return;
    float x = sp[3 * j], y = sp[3 * j + 1], z = sp[3 * j + 2];
    int cid = (cell_coord(z) * GD + cell_coord(y)) * GD + cell_coord(x);
    int pos = atomicAdd(&cursor[cid], 1);
    float s2 = __fadd_rn(__fadd_rn(__fmul_rn(x, x), __fmul_rn(y, y)), __fmul_rn(z, z));
    spts[pos] = make_float4(-2.f * x, -2.f * y, -2.f * z, s2);
    sidx[pos] = j;
}

// ---------------- grid kNN + interpolation ----------------
// 256 threads = 4 waves; 4 lanes (a "quad") per query -> 64 queries/block.
// Each sublane strides the cell's point list by 4; bound (3rd-best score)
// shared across the quad per shell via shfl_xor-min; exact butterfly merge.
// Scoring is the FROZEN formula (R5): a = fma(z,qz, fma(y,qy, rn(x*qx)));
// d = rn(rn(t2 + a) + s2). Selection by lexicographic (d, j).
__global__ __launch_bounds__(256) void k_knn(const float4* __restrict__ spts,
        const int* __restrict__ sidx, const int* __restrict__ offs,
        const float* __restrict__ feat, const float* __restrict__ tp,
        float* __restrict__ out, int M, int C) {
    __shared__ float s_w[3][64];
    __shared__ int   s_j[3][64];

    const int tid  = threadIdx.x;
    const int lane = tid & 63;
    const int wave = tid >> 6;
    const int sub  = lane & 3;
    const int qloc = wave * 16 + (lane >> 2);   // 0..63
    const int q    = blockIdx.x * 64 + qloc;

    float qx = 0.f, qy = 0.f, qz = 0.f;
    const bool valid = q < M;
    if (valid) { qx = tp[3 * q]; qy = tp[3 * q + 1]; qz = tp[3 * q + 2]; }
    const float t2 = __fadd_rn(__fadd_rn(__fmul_rn(qx, qx), __fmul_rn(qy, qy)),
                               __fmul_rn(qz, qz));
    const int cqx = cell_coord(qx), cqy = cell_coord(qy), cqz = cell_coord(qz);

    unsigned long long k0 = ~0ULL, k1 = ~0ULL, k2 = ~0ULL;
    float bound = __uint_as_float(0x7f800000u);   // +inf until 3 found

    if (valid) {
        for (int s = 0; s < GD; ++s) {
            if (s >= 2) {
                // nearest point in shell s is >= (s-1)*CELL away (q inside its cell)
                float ring = (float)(s - 1) * CELL_SZ;
                if (ring * ring > bound + MARGIN) break;
            }
            for (int dz = -s; dz <= s; ++dz) {
                int cz = cqz + dz;
                if ((unsigned)cz >= GD) continue;
                for (int dy = -s; dy <= s; ++dy) {
                    int cy = cqy + dy;
                    if ((unsigned)cy >= GD) continue;
                    bool face = (dz == -s || dz == s || dy == -s || dy == s);
                    int step = face ? 1 : 2 * s;   // s==0 -> face true -> step 1
                    for (int dx = -s; dx <= s; dx += step) {
                        int cx = cqx + dx;
                        if ((unsigned)cx >= GD) continue;
                        // conservative min dist^2 from q to this cell's box
                        float bx = BOX_LO + cx * CELL_SZ;
                        float by = BOX_LO + cy * CELL_SZ;
                        float bz = BOX_LO + cz * CELL_SZ;
                        float ax = fmaxf(fmaxf(bx - qx, qx - (bx + CELL_SZ)), 0.f);
                        float ay = fmaxf(fmaxf(by - qy, qy - (by + CELL_SZ)), 0.f);
                        float az = fmaxf(fmaxf(bz - qz, qz - (bz + CELL_SZ)), 0.f);
                        float mind2 = ax * ax + ay * ay + az * az;
                        if (mind2 > bound + MARGIN) continue;
                        int cid = (cz * GD + cy) * GD + cx;
                        int beg = offs[cid], end = offs[cid + 1];
                        for (int p = beg + sub; p < end; p += 4) {
                            float4 pt = spts[p];
                            int j = sidx[p];
                            // FROZEN score (R5) — do not change
                            float a = fmaf(pt.z, qz, fmaf(pt.y, qy, __fmul_rn(pt.x, qx)));
                            float d = __fadd_rn(__fadd_rn(t2, a), pt.w);
                            unsigned long long k =
                                ((unsigned long long)key_hi(d) << 32) | (unsigned)j;
                            insert3k(k, k0, k1, k2);
                        }
                    }
                }
            }
            // share the 3rd-best bound across the quad (stale-high is safe)
            float d2f = (k2 == ~0ULL) ? __uint_as_float(0x7f800000u) : key_d(k2);
            d2f = fminf(d2f, __shfl_xor(d2f, 1, 64));
            d2f = fminf(d2f, __shfl_xor(d2f, 2, 64));
            bound = d2f;
        }
    }

    // exact butterfly merge of the quad's disjoint top-3 sets
    for (int r = 1; r <= 2; r <<= 1) {
        unsigned long long m0 = shfl_xor_u64(k0, r);
        unsigned long long m1 = shfl_xor_u64(k1, r);
        unsigned long long m2 = shfl_xor_u64(k2, r);
        insert3k(m0, k0, k1, k2);
        insert3k(m1, k0, k1, k2);
        insert3k(m2, k0, k1, k2);
    }

    if (valid && sub == 0) {
        float b0 = key_d(k0), b1 = key_d(k1), b2 = key_d(k2);
        // FROZEN weights: w = 1/(d+eps); w /= (w0+w1)+w2
        float w0 = __fdiv_rn(1.f, __fadd_rn(b0, EPS));
        float w1 = __fdiv_rn(1.f, __fadd_rn(b1, EPS));
        float w2 = __fdiv_rn(1.f, __fadd_rn(b2, EPS));
        float sum = __fadd_rn(__fadd_rn(w0, w1), w2);
        s_w[0][qloc] = __fdiv_rn(w0, sum);
        s_w[1][qloc] = __fdiv_rn(w1, sum);
        s_w[2][qloc] = __fdiv_rn(w2, sum);
        s_j[0][qloc] = (int)(unsigned)(k0 & 0xffffffffu);
        s_j[1][qloc] = (int)(unsigned)(k1 & 0xffffffffu);
        s_j[2][qloc] = (int)(unsigned)(k2 & 0xffffffffu);
    }
    __syncthreads();

    // interpolation: 4 threads/query, each C/16 float4s of the row
    const int tm = tid >> 2;
    const int qq = tid & 3;
    const int gm = blockIdx.x * 64 + tm;
    if (gm < M) {
        const int nv = C >> 4;
        const float w0 = s_w[0][tm], w1 = s_w[1][tm], w2 = s_w[2][tm];
        const float4* f0 = (const float4*)(feat + (size_t)s_j[0][tm] * C) + qq * nv;
        const float4* f1 = (const float4*)(feat + (size_t)s_j[1][tm] * C) + qq * nv;
        const float4* f2 = (const float4*)(feat + (size_t)s_j[2][tm] * C) + qq * nv;
        float4* o = (float4*)(out + (size_t)gm * C) + qq * nv;
        for (int r = 0; r < nv; ++r) {
            float4 a = f0[r], b = f1[r], c = f2[r];
            float4 v;
            v.x = w0 * a.x + w1 * b.x + w2 * c.x;
            v.y = w0 * a.y + w1 * b.y + w2 * c.y;
            v.z = w0 * a.z + w1 * b.z + w2 * c.z;
            v.w = w0 * a.w + w1 * b.w + w2 * c.w;
            o[r] = v;
        }
    }
}

// ---------------- dense fallback (validated R7 path) ----------------
#define NW 16
__global__ void knn_preproc(const float* __restrict__ sp, float4* __restrict__ sp4, int N) {
    int j = blockIdx.x * blockDim.x + threadIdx.x;
    if (j < N) {
        float x = sp[3 * j + 0], y = sp[3 * j + 1], z = sp[3 * j + 2];
        float s2 = __fadd_rn(__fadd_rn(__fmul_rn(x, x), __fmul_rn(y, y)), __fmul_rn(z, z));
        sp4[j] = make_float4(-2.f * x, -2.f * y, -2.f * z, s2);
    }
}
__device__ __forceinline__ void insert3_bl(float d, int j,
                                           float& d0, float& d1, float& d2,
                                           int& i0, int& i1, int& i2) {
    const bool c0 = d < d0, c1 = d < d1, c2 = d < d2;
    const float nd2 = c1 ? d1 : (c2 ? d : d2);
    const int   ni2 = c1 ? i1 : (c2 ? j : i2);
    const float nd1 = c0 ? d0 : (c1 ? d : d1);
    const int   ni1 = c0 ? i0 : (c1 ? j : i1);
    const float nd0 = c0 ? d : d0;
    const int   ni0 = c0 ? j : i0;
    d0 = nd0; d1 = nd1; d2 = nd2;
    i0 = ni0; i1 = ni1; i2 = ni2;
}
#define SCORE_INSERT(p, jv) do {                                          \
    float _a = fmaf((p).z, tz, fmaf((p).y, ty, __fmul_rn((p).x, tx)));    \
    float _d = __fadd_rn(__fadd_rn(t2, _a), (p).w);                       \
    if (__any(_d < d2))                                                   \
        insert3_bl(_d, (jv), d0, d1, d2, i0, i1, i2);                     \
} while (0)
__global__ __launch_bounds__(1024, 8) void knn_dense(
    const float4* __restrict__ sp4, const float* __restrict__ feat,
    const float* __restrict__ tp, float* __restrict__ out,
    int N, int M, int C) {
    __shared__ float s_d[NW][3][64];
    __shared__ int   s_i[NW][3][64];
    __shared__ float s_w[3][64];
    __shared__ int   s_j[3][64];
    const int tid  = threadIdx.x;
    const int lane = tid & 63;
    const int wave = __builtin_amdgcn_readfirstlane(tid >> 6);
    const int mbase = blockIdx.x * 64;
    const int m = mbase + lane;
    float tx = 0.f, ty = 0.f, tz = 0.f;
    if (m < M) { tx = tp[3 * m + 0]; ty = tp[3 * m + 1]; tz = tp[3 * m + 2]; }
    const float t2 = __fadd_rn(__fadd_rn(__fmul_rn(tx, tx), __fmul_rn(ty, ty)),
                               __fmul_rn(tz, tz));
    float d0 = FMAXV, d1 = FMAXV, d2 = FMAXV;
    int   i0 = 0,     i1 = 0,     i2 = 0;
    const int chunk = (N + NW - 1) / NW;
    const int jbeg = wave * chunk;
    const int jend = min(jbeg + chunk, N);
    int j = jbeg;
    for (; j + 8 <= jend; j += 8) {
        float4 p0 = sp4[j + 0], p1 = sp4[j + 1], p2 = sp4[j + 2], p3 = sp4[j + 3];
        float4 p4 = sp4[j + 4], p5 = sp4[j + 5], p6 = sp4[j + 6], p7 = sp4[j + 7];
        SCORE_INSERT(p0, j + 0); SCORE_INSERT(p1, j + 1);
        SCORE_INSERT(p2, j + 2); SCORE_INSERT(p3, j + 3);
        SCORE_INSERT(p4, j + 4); SCORE_INSERT(p5, j + 5);
        SCORE_INSERT(p6, j + 6); SCORE_INSERT(p7, j + 7);
    }
    for (; j < jend; ++j) { float4 p = sp4[j]; SCORE_INSERT(p, j); }
    s_d[wave][0][lane] = d0; s_d[wave][1][lane] = d1; s_d[wave][2][lane] = d2;
    s_i[wave][0][lane] = i0; s_i[wave][1][lane] = i1; s_i[wave][2][lane] = i2;
    __syncthreads();
    if (wave == 0) {
        float b0 = FMAXV, b1 = FMAXV, b2 = FMAXV;
        int   j0 = 0,     j1 = 0,     j2 = 0;
        #pragma unroll
        for (int w = 0; w < NW; ++w)
            #pragma unroll
            for (int k = 0; k < 3; ++k)
                insert3_bl(s_d[w][k][lane], s_i[w][k][lane], b0, b1, b2, j0, j1, j2);
        float w0 = __fdiv_rn(1.f, __fadd_rn(b0, EPS));
        float w1 = __fdiv_rn(1.f, __fadd_rn(b1, EPS));
        float w2 = __fdiv_rn(1.f, __fadd_rn(b2, EPS));
        float sum = __fadd_rn(__fadd_rn(w0, w1), w2);
        s_w[0][lane] = __fdiv_rn(w0, sum);
        s_w[1][lane] = __fdiv_rn(w1, sum);
        s_w[2][lane] = __fdiv_rn(w2, sum);
        s_j[0][lane] = j0; s_j[1][lane] = j1; s_j[2][lane] = j2;
    }
    __syncthreads();
    const int tm = tid >> 4;
    const int qq = tid & 15;
    const int gm = mbase + tm;
    if (gm < M) {
        const int nv = C >> 6;
        const float w0 = s_w[0][tm], w1 = s_w[1][tm], w2 = s_w[2][tm];
        const float4* f0 = (const float4*)(feat + (size_t)s_j[0][tm] * C) + qq * nv;
        const float4* f1 = (const float4*)(feat + (size_t)s_j[1][tm] * C) + qq * nv;
        const float4* f2 = (const float4*)(feat + (size_t)s_j[2][tm] * C) + qq * nv;
        float4* o = (float4*)(out + (size_t)gm * C) + qq * nv;
        for (int r = 0; r < nv; ++r) {
            float4 a = f0[r], b = f1[r], c = f2[r];
            float4 v;
            v.x = w0 * a.x + w1 * b.x + w2 * c.x;
            v.y = w0 * a.y + w1 * b.y + w2 * c.y;
            v.z = w0 * a.z + w1 * b.z + w2 * c.z;
            v.w = w0 * a.w + w1 * b.w + w2 * c.w;
            o[r] = v;
        }
    }
}

// ---------------- host ----------------
static inline size_t align256(size_t x) { return (x + 255) & ~(size_t)255; }

extern "C" void kernel_launch(void* const* d_in, const int* in_sizes, int n_in,
                              void* d_out, int out_size, void* d_ws, size_t ws_size,
                              hipStream_t stream) {
    const float* sp   = (const float*)d_in[0];  // source_points [N,3]
    const float* feat = (const float*)d_in[1];  // source_features [N,C]
    const float* tp   = (const float*)d_in[2];  // target_points [M,3]
    float* out = (float*)d_out;                 // [M,C] fp32

    const int N = in_sizes[0] / 3;
    const int C = in_sizes[1] / N;
    const int M = in_sizes[2] / 3;

    // ws layout for the grid path
    size_t oOffs   = 0;                                        // (CELLS+1) ints
    size_t oCursor = align256(oOffs + (size_t)(CELLS + 1) * 4); // CELLS ints (counts, then cursor)
    size_t oBsum   = align256(oCursor + (size_t)CELLS * 4);     // 256 ints
    size_t oBbase  = align256(oBsum + 256 * 4);                 // 256 ints
    size_t oPts    = align256(oBbase + 256 * 4);                // N float4
    size_t oIdx    = align256(oPts + (size_t)N * 16);           // N ints
    size_t need    = oIdx + (size_t)N * 4;

    if (ws_size >= need) {
        char* ws = (char*)d_ws;
        int*    offs   = (int*)(ws + oOffs);
        int*    cursor = (int*)(ws + oCursor);
        int*    bsum   = (int*)(ws + oBsum);
        int*    bbase  = (int*)(ws + oBbase);
        float4* spts   = (float4*)(ws + oPts);
        int*    sidx   = (int*)(ws + oIdx);

        hipMemsetAsync(cursor, 0, (size_t)CELLS * 4, stream);
        k_hist<<<(N + 255) / 256, 256, 0, stream>>>(sp, cursor, N);
        k_scanA<<<CELLS / 1024, 1024, 0, stream>>>(cursor, offs, bsum);
        k_scanB<<<1, 256, 0, stream>>>(bsum, bbase);
        k_scanC<<<CELLS / 1024, 1024, 0, stream>>>(offs, cursor, bbase, N);
        k_scatter<<<(N + 255) / 256, 256, 0, stream>>>(sp, cursor, spts, sidx, N);
        k_knn<<<(M + 63) / 64, 256, 0, stream>>>(spts, sidx, offs, feat, tp, out, M, C);
    } else {
        // dense fallback (validated R7)
        float4* sp4 = (float4*)d_ws;
        knn_preproc<<<(N + 255) / 256, 256, 0, stream>>>(sp, sp4, N);
        knn_dense<<<(M + 63) / 64, 1024, 0, stream>>>(sp4, feat, tp, out, N, M, C);
    }
}

// Round 9
// 354.086 us; speedup vs baseline: 3.7255x; 3.7255x over previous
//
#include <hip/hip_runtime.h>
#include <math.h>
#include <stdint.h>

#define EPS 1e-8f
#define FMAXV 3.402823466e38f

// ---------------- 1-D x-sweep parameters ----------------
#define NB 1024
#define BLO (-6.0f)
#define BW (0.01171875f)        // 12/1024, exact in fp32; i*BW and BLO+i*BW exact
#define INVBW (85.333336f)      // monotone mapping is all we need
#define MARGIN 2e-4f            // >> max |frozen score - true dist^2| (~4e-5)

__device__ __forceinline__ int cell1d(float x) {
    int c = (int)floorf((x - BLO) * INVBW);
    return min(max(c, 0), NB - 1);
}
__device__ __forceinline__ float finf() { return __uint_as_float(0x7f800000u); }

// Monotone float->uint key; (key_hi(d)<<32)|idx gives lexicographic (d, idx)
// ordering == jax.lax.top_k with lowest-index tie-break (validated R8).
__device__ __forceinline__ unsigned key_hi(float d) {
    unsigned b = __float_as_uint(d);
    return (b & 0x80000000u) ? ~b : (b | 0x80000000u);
}
__device__ __forceinline__ float key_d(unsigned long long k) {
    unsigned h = (unsigned)(k >> 32);
    unsigned b = (h & 0x80000000u) ? (h & 0x7fffffffu) : ~h;
    return __uint_as_float(b);
}
__device__ __forceinline__ float bound3(unsigned long long k2) {
    return (k2 == ~0ULL) ? finf() : key_d(k2);
}
__device__ __forceinline__ unsigned long long shfl_xor_u64(unsigned long long v, int m) {
    int lo = __shfl_xor((int)(unsigned)(v & 0xffffffffu), m, 64);
    int hi = __shfl_xor((int)(unsigned)(v >> 32), m, 64);
    return ((unsigned long long)(unsigned)hi << 32) | (unsigned)lo;
}
// Branchless sorted top-3 insert on u64 keys (strict '<' lexicographic).
__device__ __forceinline__ void insert3k(unsigned long long k,
        unsigned long long& k0, unsigned long long& k1, unsigned long long& k2) {
    const bool c0 = k < k0, c1 = k < k1, c2 = k < k2;
    k2 = c1 ? k1 : (c2 ? k : k2);
    k1 = c0 ? k0 : (c1 ? k : k1);
    k0 = c0 ? k : k0;
}

// ---------------- build: fused histogram / scan / scatter ----------------
__global__ void k_hist2(const float* __restrict__ sp, int N,
                        const float* __restrict__ tp, int M,
                        int* __restrict__ scnt, int* __restrict__ qcnt) {
    int i = blockIdx.x * 256 + threadIdx.x;
    if (i < N) {
        atomicAdd(&scnt[cell1d(sp[3 * i])], 1);
    } else if (i < N + M) {
        int j = i - N;
        atomicAdd(&qcnt[cell1d(tp[3 * j])], 1);
    }
}

// blockIdx 0 -> source arrays, 1 -> query arrays. cnt becomes the cursor.
__global__ __launch_bounds__(1024) void k_scan2(int* __restrict__ scnt, int* __restrict__ soffs,
                                                int* __restrict__ qcnt, int* __restrict__ qoffs) {
    int* cnt  = blockIdx.x ? qcnt : scnt;
    int* offs = blockIdx.x ? qoffs : soffs;
    __shared__ int sh[NB];
    int v = cnt[threadIdx.x];
    sh[threadIdx.x] = v;
    __syncthreads();
    for (int o = 1; o < NB; o <<= 1) {
        int t = (threadIdx.x >= (unsigned)o) ? sh[threadIdx.x - o] : 0;
        __syncthreads();
        sh[threadIdx.x] += t;
        __syncthreads();
    }
    int excl = sh[threadIdx.x] - v;
    cnt[threadIdx.x]  = excl;   // cursor for scatter
    offs[threadIdx.x] = excl;
    if (threadIdx.x == NB - 1) offs[NB] = sh[NB - 1];
}

// Scatter sources (with FROZEN preproc, validated R5/R8) and queries.
__global__ void k_scat2(const float* __restrict__ sp, int N,
                        const float* __restrict__ tp, int M,
                        int* __restrict__ scur, float4* __restrict__ spts, int* __restrict__ sidx,
                        int* __restrict__ qcur, float4* __restrict__ qpts) {
    int i = blockIdx.x * 256 + threadIdx.x;
    if (i < N) {
        float x = sp[3 * i], y = sp[3 * i + 1], z = sp[3 * i + 2];
        int pos = atomicAdd(&scur[cell1d(x)], 1);
        float s2 = __fadd_rn(__fadd_rn(__fmul_rn(x, x), __fmul_rn(y, y)), __fmul_rn(z, z));
        spts[pos] = make_float4(-2.f * x, -2.f * y, -2.f * z, s2);
        sidx[pos] = i;
    } else if (i < N + M) {
        int j = i - N;
        float x = tp[3 * j], y = tp[3 * j + 1], z = tp[3 * j + 2];
        int pos = atomicAdd(&qcur[cell1d(x)], 1);
        qpts[pos] = make_float4(x, y, z, __int_as_float(j));
    }
}

// ---------------- sweep kNN + interpolation ----------------
// 256 threads = 4 waves; each wave owns 4 x-adjacent (sorted) queries with
// 16 lanes each (sub = lane&15 strides candidates). Sweep buckets outward
// from the wave's center bucket; per-query bound = min over its 16 lanes of
// the 3rd-best FROZEN score; stop when next-bucket x-dist^2 > bound+MARGIN
// for every lane. All surviving candidates scored with the FROZEN formula
// (R5) and selected via u64 (score,idx) keys (R8) -> order-independent,
// bit-exact vs reference.
__global__ __launch_bounds__(256) void k_knn(
        const float4* __restrict__ spts, const int* __restrict__ sidx,
        const int* __restrict__ soffs, const float4* __restrict__ qpts,
        const float* __restrict__ feat, float* __restrict__ out, int M, int C) {
    __shared__ float s_w[3][16];
    __shared__ int   s_j[3][16];
    __shared__ int   s_o[16];

    const int tid  = threadIdx.x;
    const int lane = tid & 63;
    const int sub  = lane & 15;
    const int qloc = tid >> 4;                 // 0..15 per block
    const int qid  = blockIdx.x * 16 + qloc;

    const bool valid = qid < M;
    float4 qp = valid ? qpts[qid] : make_float4(0.f, 0.f, 0.f, 0.f);
    const float qx = qp.x, qy = qp.y, qz = qp.z;
    const int orig = __float_as_int(qp.w);
    const float t2 = __fadd_rn(__fadd_rn(__fmul_rn(qx, qx), __fmul_rn(qy, qy)),
                               __fmul_rn(qz, qz));

    // wave-uniform center bucket (mid of min/max x over the wave)
    float xmn = qx, xmx = qx;
    #pragma unroll
    for (int r = 1; r < 64; r <<= 1) {
        xmn = fminf(xmn, __shfl_xor(xmn, r, 64));
        xmx = fmaxf(xmx, __shfl_xor(xmx, r, 64));
    }
    const int c0 = cell1d(0.5f * (xmn + xmx));

    unsigned long long k0 = ~0ULL, k1 = ~0ULL, k2 = ~0ULL;
    float d2f = finf();

    #define SCANB(b) do {                                                      \
        if ((unsigned)(b) < NB) {                                              \
            int beg = __builtin_amdgcn_readfirstlane(soffs[(b)]);              \
            int end = __builtin_amdgcn_readfirstlane(soffs[(b) + 1]);          \
            for (int p = beg + sub; p < end; p += 16) {                        \
                float4 pt = spts[p];                                           \
                int sj = sidx[p];                                              \
                float a = fmaf(pt.z, qz, fmaf(pt.y, qy, __fmul_rn(pt.x, qx))); \
                float d = __fadd_rn(__fadd_rn(t2, a), pt.w);                   \
                if (__any(d <= d2f)) {                                         \
                    unsigned long long kk =                                    \
                        ((unsigned long long)key_hi(d) << 32) | (unsigned)sj;  \
                    insert3k(kk, k0, k1, k2);                                  \
                    d2f = bound3(k2);                                          \
                }                                                              \
            }                                                                  \
        }                                                                      \
    } while (0)

    for (int k = 0; k <= NB; ++k) {
        SCANB(c0 - k);
        if (k > 0) SCANB(c0 + k);

        // per-query bound: min over the query's 16 lanes (conservative >= true d3)
        float bnd = d2f;
        bnd = fminf(bnd, __shfl_xor(bnd, 1, 64));
        bnd = fminf(bnd, __shfl_xor(bnd, 2, 64));
        bnd = fminf(bnd, __shfl_xor(bnd, 4, 64));
        bnd = fminf(bnd, __shfl_xor(bnd, 8, 64));

        const int nbl = c0 - k - 1, nbr = c0 + k + 1;
        // exact edges: BLO + i*BW representable exactly for 0<=i<=NB
        const float dl = qx - (BLO + (float)(nbl + 1) * BW);  // to right edge of next-left
        const float dr = (BLO + (float)nbr * BW) - qx;        // to left edge of next-right
        const bool pl = (nbl < 0)   || (dl > 0.f && dl * dl > bnd + MARGIN);
        const bool pr = (nbr >= NB) || (dr > 0.f && dr * dr > bnd + MARGIN);
        const bool done = (!valid) || (pl && pr);
        if (__all(done)) break;
    }
    #undef SCANB

    // butterfly merge of the 16 disjoint partial top-3 sets (exact, R8-style)
    #pragma unroll
    for (int r = 1; r <= 8; r <<= 1) {
        unsigned long long m0 = shfl_xor_u64(k0, r);
        unsigned long long m1 = shfl_xor_u64(k1, r);
        unsigned long long m2 = shfl_xor_u64(k2, r);
        insert3k(m0, k0, k1, k2);
        insert3k(m1, k0, k1, k2);
        insert3k(m2, k0, k1, k2);
    }

    if (valid && sub == 0) {
        float b0 = key_d(k0), b1 = key_d(k1), b2 = key_d(k2);
        // FROZEN weights (R5): w = 1/(d+eps); w /= (w0+w1)+w2
        float w0 = __fdiv_rn(1.f, __fadd_rn(b0, EPS));
        float w1 = __fdiv_rn(1.f, __fadd_rn(b1, EPS));
        float w2 = __fdiv_rn(1.f, __fadd_rn(b2, EPS));
        float sum = __fadd_rn(__fadd_rn(w0, w1), w2);
        s_w[0][qloc] = __fdiv_rn(w0, sum);
        s_w[1][qloc] = __fdiv_rn(w1, sum);
        s_w[2][qloc] = __fdiv_rn(w2, sum);
        s_j[0][qloc] = (int)(unsigned)(k0 & 0xffffffffu);
        s_j[1][qloc] = (int)(unsigned)(k1 & 0xffffffffu);
        s_j[2][qloc] = (int)(unsigned)(k2 & 0xffffffffu);
        s_o[qloc]    = orig;
    }
    __syncthreads();

    // interpolation: 16 threads per query row, float4 loads/stores (C%64==0)
    const int tm = tid >> 4;
    const int qq = tid & 15;
    if (blockIdx.x * 16 + tm < M) {
        const int nv = C >> 6;                 // float4s per 1/16 row slice
        const int row = s_o[tm];
        const float w0 = s_w[0][tm], w1 = s_w[1][tm], w2 = s_w[2][tm];
        const float4* f0 = (const float4*)(feat + (size_t)s_j[0][tm] * C) + qq * nv;
        const float4* f1 = (const float4*)(feat + (size_t)s_j[1][tm] * C) + qq * nv;
        const float4* f2 = (const float4*)(feat + (size_t)s_j[2][tm] * C) + qq * nv;
        float4* o = (float4*)(out + (size_t)row * C) + qq * nv;
        for (int r = 0; r < nv; ++r) {
            float4 a = f0[r], b = f1[r], c = f2[r];
            float4 v;
            v.x = w0 * a.x + w1 * b.x + w2 * c.x;
            v.y = w0 * a.y + w1 * b.y + w2 * c.y;
            v.z = w0 * a.z + w1 * b.z + w2 * c.z;
            v.w = w0 * a.w + w1 * b.w + w2 * c.w;
            o[r] = v;
        }
    }
}

// ---------------- dense fallback (validated R7 path) ----------------
#define NW 16
__global__ void knn_preproc(const float* __restrict__ sp, float4* __restrict__ sp4, int N) {
    int j = blockIdx.x * blockDim.x + threadIdx.x;
    if (j < N) {
        float x = sp[3 * j + 0], y = sp[3 * j + 1], z = sp[3 * j + 2];
        float s2 = __fadd_rn(__fadd_rn(__fmul_rn(x, x), __fmul_rn(y, y)), __fmul_rn(z, z));
        sp4[j] = make_float4(-2.f * x, -2.f * y, -2.f * z, s2);
    }
}
__device__ __forceinline__ void insert3_bl(float d, int j,
                                           float& d0, float& d1, float& d2,
                                           int& i0, int& i1, int& i2) {
    const bool c0 = d < d0, c1 = d < d1, c2 = d < d2;
    const float nd2 = c1 ? d1 : (c2 ? d : d2);
    const int   ni2 = c1 ? i1 : (c2 ? j : i2);
    const float nd1 = c0 ? d0 : (c1 ? d : d1);
    const int   ni1 = c0 ? i0 : (c1 ? j : i1);
    const float nd0 = c0 ? d : d0;
    const int   ni0 = c0 ? j : i0;
    d0 = nd0; d1 = nd1; d2 = nd2;
    i0 = ni0; i1 = ni1; i2 = ni2;
}
#define SCORE_INSERT(p, jv) do {                                          \
    float _a = fmaf((p).z, tz, fmaf((p).y, ty, __fmul_rn((p).x, tx)));    \
    float _d = __fadd_rn(__fadd_rn(t2, _a), (p).w);                       \
    if (__any(_d < d2))                                                   \
        insert3_bl(_d, (jv), d0, d1, d2, i0, i1, i2);                     \
} while (0)
__global__ __launch_bounds__(1024, 8) void knn_dense(
    const float4* __restrict__ sp4, const float* __restrict__ feat,
    const float* __restrict__ tp, float* __restrict__ out,
    int N, int M, int C) {
    __shared__ float s_d[NW][3][64];
    __shared__ int   s_i[NW][3][64];
    __shared__ float s_w[3][64];
    __shared__ int   s_j[3][64];
    const int tid  = threadIdx.x;
    const int lane = tid & 63;
    const int wave = __builtin_amdgcn_readfirstlane(tid >> 6);
    const int mbase = blockIdx.x * 64;
    const int m = mbase + lane;
    float tx = 0.f, ty = 0.f, tz = 0.f;
    if (m < M) { tx = tp[3 * m + 0]; ty = tp[3 * m + 1]; tz = tp[3 * m + 2]; }
    const float t2 = __fadd_rn(__fadd_rn(__fmul_rn(tx, tx), __fmul_rn(ty, ty)),
                               __fmul_rn(tz, tz));
    float d0 = FMAXV, d1 = FMAXV, d2 = FMAXV;
    int   i0 = 0,     i1 = 0,     i2 = 0;
    const int chunk = (N + NW - 1) / NW;
    const int jbeg = wave * chunk;
    const int jend = min(jbeg + chunk, N);
    int j = jbeg;
    for (; j + 8 <= jend; j += 8) {
        float4 p0 = sp4[j + 0], p1 = sp4[j + 1], p2 = sp4[j + 2], p3 = sp4[j + 3];
        float4 p4 = sp4[j + 4], p5 = sp4[j + 5], p6 = sp4[j + 6], p7 = sp4[j + 7];
        SCORE_INSERT(p0, j + 0); SCORE_INSERT(p1, j + 1);
        SCORE_INSERT(p2, j + 2); SCORE_INSERT(p3, j + 3);
        SCORE_INSERT(p4, j + 4); SCORE_INSERT(p5, j + 5);
        SCORE_INSERT(p6, j + 6); SCORE_INSERT(p7, j + 7);
    }
    for (; j < jend; ++j) { float4 p = sp4[j]; SCORE_INSERT(p, j); }
    s_d[wave][0][lane] = d0; s_d[wave][1][lane] = d1; s_d[wave][2][lane] = d2;
    s_i[wave][0][lane] = i0; s_i[wave][1][lane] = i1; s_i[wave][2][lane] = i2;
    __syncthreads();
    if (wave == 0) {
        float b0 = FMAXV, b1 = FMAXV, b2 = FMAXV;
        int   j0 = 0,     j1 = 0,     j2 = 0;
        #pragma unroll
        for (int w = 0; w < NW; ++w)
            #pragma unroll
            for (int k = 0; k < 3; ++k)
                insert3_bl(s_d[w][k][lane], s_i[w][k][lane], b0, b1, b2, j0, j1, j2);
        float w0 = __fdiv_rn(1.f, __fadd_rn(b0, EPS));
        float w1 = __fdiv_rn(1.f, __fadd_rn(b1, EPS));
        float w2 = __fdiv_rn(1.f, __fadd_rn(b2, EPS));
        float sum = __fadd_rn(__fadd_rn(w0, w1), w2);
        s_w[0][lane] = __fdiv_rn(w0, sum);
        s_w[1][lane] = __fdiv_rn(w1, sum);
        s_w[2][lane] = __fdiv_rn(w2, sum);
        s_j[0][lane] = j0; s_j[1][lane] = j1; s_j[2][lane] = j2;
    }
    __syncthreads();
    const int tm = tid >> 4;
    const int qq = tid & 15;
    const int gm = mbase + tm;
    if (gm < M) {
        const int nv = C >> 6;
        const float w0 = s_w[0][tm], w1 = s_w[1][tm], w2 = s_w[2][tm];
        const float4* f0 = (const float4*)(feat + (size_t)s_j[0][tm] * C) + qq * nv;
        const float4* f1 = (const float4*)(feat + (size_t)s_j[1][tm] * C) + qq * nv;
        const float4* f2 = (const float4*)(feat + (size_t)s_j[2][tm] * C) + qq * nv;
        float4* o = (float4*)(out + (size_t)gm * C) + qq * nv;
        for (int r = 0; r < nv; ++r) {
            float4 a = f0[r], b = f1[r], c = f2[r];
            float4 v;
            v.x = w0 * a.x + w1 * b.x + w2 * c.x;
            v.y = w0 * a.y + w1 * b.y + w2 * c.y;
            v.z = w0 * a.z + w1 * b.z + w2 * c.z;
            v.w = w0 * a.w + w1 * b.w + w2 * c.w;
            o[r] = v;
        }
    }
}

// ---------------- host ----------------
static inline size_t align256(size_t x) { return (x + 255) & ~(size_t)255; }

extern "C" void kernel_launch(void* const* d_in, const int* in_sizes, int n_in,
                              void* d_out, int out_size, void* d_ws, size_t ws_size,
                              hipStream_t stream) {
    const float* sp   = (const float*)d_in[0];  // source_points [N,3]
    const float* feat = (const float*)d_in[1];  // source_features [N,C]
    const float* tp   = (const float*)d_in[2];  // target_points [M,3]
    float* out = (float*)d_out;                 // [M,C] fp32

    const int N = in_sizes[0] / 3;
    const int C = in_sizes[1] / N;
    const int M = in_sizes[2] / 3;

    // ws layout (sweep path)
    size_t oScnt  = 0;                                   // NB ints (then cursor)
    size_t oQcnt  = oScnt + (size_t)NB * 4;              // NB ints (adjacent -> one memset)
    size_t oSoffs = align256(oQcnt + (size_t)NB * 4);    // NB+1 ints
    size_t oQoffs = align256(oSoffs + (size_t)(NB + 1) * 4);
    size_t oSpts  = align256(oQoffs + (size_t)(NB + 1) * 4);  // N float4
    size_t oSidx  = align256(oSpts + (size_t)N * 16);         // N ints
    size_t oQpts  = align256(oSidx + (size_t)N * 4);          // M float4
    size_t need   = oQpts + (size_t)M * 16;

    if (ws_size >= need && (C & 63) == 0) {
        char* ws = (char*)d_ws;
        int*    scnt  = (int*)(ws + oScnt);
        int*    qcnt  = (int*)(ws + oQcnt);
        int*    soffs = (int*)(ws + oSoffs);
        int*    qoffs = (int*)(ws + oQoffs);
        float4* spts  = (float4*)(ws + oSpts);
        int*    sidxp = (int*)(ws + oSidx);
        float4* qpts  = (float4*)(ws + oQpts);

        hipMemsetAsync(scnt, 0, (size_t)2 * NB * 4, stream);
        int nmBlocks = (N + M + 255) / 256;
        k_hist2<<<nmBlocks, 256, 0, stream>>>(sp, N, tp, M, scnt, qcnt);
        k_scan2<<<2, NB, 0, stream>>>(scnt, soffs, qcnt, qoffs);
        k_scat2<<<nmBlocks, 256, 0, stream>>>(sp, N, tp, M, scnt, spts, sidxp, qcnt, qpts);
        k_knn<<<(M + 15) / 16, 256, 0, stream>>>(spts, sidxp, soffs, qpts, feat, out, M, C);
    } else {
        // dense fallback (validated R7)
        float4* sp4 = (float4*)d_ws;
        knn_preproc<<<(N + 255) / 256, 256, 0, stream>>>(sp, sp4, N);
        knn_dense<<<(M + 63) / 64, 1024, 0, stream>>>(sp4, feat, tp, out, N, M, C);
    }
}

// Round 10
// 260.300 us; speedup vs baseline: 5.0678x; 1.3603x over previous
//
#include <hip/hip_runtime.h>
#include <math.h>
#include <stdint.h>

#define EPS 1e-8f
#define FMAXV 3.402823466e38f

// ---------------- 1-D x-sweep parameters ----------------
#define NB 1024
#define BLO (-6.0f)
#define BW  (0.01171875f)       // 12/1024
#define INVBW (85.333336f)      // only monotone consistency needed
#define MARGIN 2e-4f            // >> max |frozen score - true dist^2| (~4e-5)
#define KPAD 13                 // round-0 half-window (~0.15) in buckets

__device__ __forceinline__ int cell1d(float x) {
    int c = (int)floorf((x - BLO) * INVBW);
    return min(max(c, 0), NB - 1);
}
__device__ __forceinline__ float finf() { return __uint_as_float(0x7f800000u); }

// Monotone float->uint key; (key_hi(d)<<32)|idx = lexicographic (d, idx)
// == jax.lax.top_k with lowest-index tie-break (validated R8/R9).
__device__ __forceinline__ unsigned key_hi(float d) {
    unsigned b = __float_as_uint(d);
    return (b & 0x80000000u) ? ~b : (b | 0x80000000u);
}
__device__ __forceinline__ float key_d(unsigned long long k) {
    unsigned h = (unsigned)(k >> 32);
    unsigned b = (h & 0x80000000u) ? (h & 0x7fffffffu) : ~h;
    return __uint_as_float(b);
}
__device__ __forceinline__ float bound3(unsigned long long k2) {
    return (k2 == ~0ULL) ? finf() : key_d(k2);
}
// Branchless sorted top-3 insert on u64 keys (strict '<' lexicographic).
__device__ __forceinline__ void insert3k(unsigned long long k,
        unsigned long long& k0, unsigned long long& k1, unsigned long long& k2) {
    const bool c0 = k < k0, c1 = k < k1, c2 = k < k2;
    k2 = c1 ? k1 : (c2 ? k : k2);
    k1 = c0 ? k0 : (c1 ? k : k1);
    k0 = c0 ? k : k0;
}

// ---------------- build: histogram / scan / scatter (validated R9) --------
__global__ void k_hist2(const float* __restrict__ sp, int N,
                        const float* __restrict__ tp, int M,
                        int* __restrict__ scnt, int* __restrict__ qcnt) {
    int i = blockIdx.x * 256 + threadIdx.x;
    if (i < N) {
        atomicAdd(&scnt[cell1d(sp[3 * i])], 1);
    } else if (i < N + M) {
        int j = i - N;
        atomicAdd(&qcnt[cell1d(tp[3 * j])], 1);
    }
}

__global__ __launch_bounds__(1024) void k_scan2(int* __restrict__ scnt, int* __restrict__ soffs,
                                                int* __restrict__ qcnt, int* __restrict__ qoffs) {
    int* cnt  = blockIdx.x ? qcnt : scnt;
    int* offs = blockIdx.x ? qoffs : soffs;
    __shared__ int sh[NB];
    int v = cnt[threadIdx.x];
    sh[threadIdx.x] = v;
    __syncthreads();
    for (int o = 1; o < NB; o <<= 1) {
        int t = (threadIdx.x >= (unsigned)o) ? sh[threadIdx.x - o] : 0;
        __syncthreads();
        sh[threadIdx.x] += t;
        __syncthreads();
    }
    int excl = sh[threadIdx.x] - v;
    cnt[threadIdx.x]  = excl;   // cursor for scatter
    offs[threadIdx.x] = excl;
    if (threadIdx.x == NB - 1) offs[NB] = sh[NB - 1];
}

// FROZEN preproc folded into scatter (validated R5/R8/R9).
__global__ void k_scat2(const float* __restrict__ sp, int N,
                        const float* __restrict__ tp, int M,
                        int* __restrict__ scur, float4* __restrict__ spts, int* __restrict__ sidx,
                        int* __restrict__ qcur, float4* __restrict__ qpts) {
    int i = blockIdx.x * 256 + threadIdx.x;
    if (i < N) {
        float x = sp[3 * i], y = sp[3 * i + 1], z = sp[3 * i + 2];
        int pos = atomicAdd(&scur[cell1d(x)], 1);
        float s2 = __fadd_rn(__fadd_rn(__fmul_rn(x, x), __fmul_rn(y, y)), __fmul_rn(z, z));
        spts[pos] = make_float4(-2.f * x, -2.f * y, -2.f * z, s2);
        sidx[pos] = i;
    } else if (i < N + M) {
        int j = i - N;
        float x = tp[3 * j], y = tp[3 * j + 1], z = tp[3 * j + 2];
        int pos = atomicAdd(&qcur[cell1d(x)], 1);
        qpts[pos] = make_float4(x, y, z, __int_as_float(j));
    }
}

// ---------------- windowed kNN (R7 structure, 2-round window) ----------------
// Block = 64 x-sorted queries (lane = query), 16 waves chunk-split contiguous
// candidate spans (8-deep scalar-load batches, R7's hot loop). Round 0: scan
// block x-range +-KPAD buckets, LDS-merge -> per-query true 3rd-best b3.
// Round 1: scan [block-union window] minus round-0 range (disjoint spans).
// Outside-window points have frozen d > b3+MARGIN-4e-5 > b3 >= final 3rd-best
// -> provably not in the frozen top-3. Scoring = FROZEN formula (R5); selection
// via u64 (score,idx) keys (R8/R9) -> order-independent, bit-exact.
#define SCORE_INS(pp, sj) do {                                                 \
    float _a = fmaf((pp).z, qz, fmaf((pp).y, qy, __fmul_rn((pp).x, qx)));      \
    float _d = __fadd_rn(__fadd_rn(t2, _a), (pp).w);                           \
    if (__any(_d <= d2f)) {                                                    \
        unsigned long long _k =                                                \
            ((unsigned long long)key_hi(_d) << 32) | (unsigned)(sj);           \
        insert3k(_k, k0, k1, k2);                                              \
        d2f = bound3(k2);                                                      \
    }                                                                          \
} while (0)

#define SCAN_SPAN(Sa, Sb) do {                                                 \
    int _len = (Sb) - (Sa);                                                    \
    if (_len > 0) {                                                            \
        int _ch = (_len + 15) >> 4;                                            \
        int _a = (Sa) + wave * _ch;                                            \
        int _b = min(_a + _ch, (Sb));                                          \
        int _p = _a;                                                           \
        for (; _p + 8 <= _b; _p += 8) {                                        \
            float4 s0 = spts[_p+0], s1 = spts[_p+1], s2v = spts[_p+2], s3 = spts[_p+3]; \
            float4 s4 = spts[_p+4], s5 = spts[_p+5], s6 = spts[_p+6], s7 = spts[_p+7]; \
            int j0 = sidx[_p+0], j1 = sidx[_p+1], j2 = sidx[_p+2], j3 = sidx[_p+3]; \
            int j4 = sidx[_p+4], j5 = sidx[_p+5], j6 = sidx[_p+6], j7 = sidx[_p+7]; \
            SCORE_INS(s0, j0); SCORE_INS(s1, j1); SCORE_INS(s2v, j2); SCORE_INS(s3, j3); \
            SCORE_INS(s4, j4); SCORE_INS(s5, j5); SCORE_INS(s6, j6); SCORE_INS(s7, j7); \
        }                                                                      \
        for (; _p < _b; ++_p) { float4 sv = spts[_p]; int jv = sidx[_p]; SCORE_INS(sv, jv); } \
    }                                                                          \
} while (0)

__global__ __launch_bounds__(1024, 8) void k_knn_blk(
        const float4* __restrict__ spts, const int* __restrict__ sidx,
        const int* __restrict__ soffs, const float4* __restrict__ qpts,
        const float* __restrict__ feat, float* __restrict__ out, int M, int C) {
    __shared__ uint2 s_k[16][3][64];   // per-wave partial top-3 (u64 keys)
    __shared__ uint2 s_m[3][64];       // merged set after round 0
    __shared__ int   s_rng[2];         // block-union round-1 bucket range
    __shared__ float s_w[3][64];
    __shared__ int   s_j[3][64];
    __shared__ int   s_o[64];

    const int tid  = threadIdx.x;
    const int lane = tid & 63;
    const int wave = __builtin_amdgcn_readfirstlane(tid >> 6);

    const int qid = blockIdx.x * 64 + lane;      // lane = query (all waves alias)
    const bool valid = qid < M;
    float4 qp = valid ? qpts[qid] : make_float4(0.f, 0.f, 0.f, __int_as_float(0));
    const float qx = qp.x, qy = qp.y, qz = qp.z;
    const int orig = __float_as_int(qp.w);
    const float t2 = __fadd_rn(__fadd_rn(__fmul_rn(qx, qx), __fmul_rn(qy, qy)),
                               __fmul_rn(qz, qz));   // FROZEN (R5)

    // block x-range (same on every wave: lanes alias the same 64 queries)
    float xm = valid ? qx : finf(), xM = valid ? qx : -finf();
    #pragma unroll
    for (int r = 1; r < 64; r <<= 1) {
        xm = fminf(xm, __shfl_xor(xm, r, 64));
        xM = fmaxf(xM, __shfl_xor(xM, r, 64));
    }
    const int c_lo = max(cell1d(xm) - KPAD, 0);
    const int c_hi = min(cell1d(xM) + KPAD, NB - 1);
    const int S0 = __builtin_amdgcn_readfirstlane(soffs[c_lo]);
    const int S1 = __builtin_amdgcn_readfirstlane(soffs[c_hi + 1]);

    unsigned long long k0 = ~0ULL, k1 = ~0ULL, k2 = ~0ULL;
    float d2f = finf();

    // ---- round 0 ----
    SCAN_SPAN(S0, S1);
    s_k[wave][0][lane] = make_uint2((unsigned)k0, (unsigned)(k0 >> 32));
    s_k[wave][1][lane] = make_uint2((unsigned)k1, (unsigned)(k1 >> 32));
    s_k[wave][2][lane] = make_uint2((unsigned)k2, (unsigned)(k2 >> 32));
    __syncthreads();

    if (wave == 0) {
        unsigned long long K0 = ~0ULL, K1 = ~0ULL, K2 = ~0ULL;
        #pragma unroll
        for (int w = 0; w < 16; ++w)
            #pragma unroll
            for (int r = 0; r < 3; ++r) {
                uint2 u = s_k[w][r][lane];
                unsigned long long k = ((unsigned long long)u.y << 32) | u.x;
                insert3k(k, K0, K1, K2);
            }
        s_m[0][lane] = make_uint2((unsigned)K0, (unsigned)(K0 >> 32));
        s_m[1][lane] = make_uint2((unsigned)K1, (unsigned)(K1 >> 32));
        s_m[2][lane] = make_uint2((unsigned)K2, (unsigned)(K2 >> 32));
        // per-query window; sqrt(inf)=inf -> full range (sparse-tail fallback)
        float b3 = bound3(K2);
        float wl = sqrtf(__fadd_rn(b3, MARGIN));
        int blo = valid ? cell1d(qx - wl) : 0x7fffffff;
        int bhi = valid ? cell1d(qx + wl) : -0x7fffffff;
        #pragma unroll
        for (int r = 1; r < 64; r <<= 1) {
            blo = min(blo, __shfl_xor(blo, r, 64));
            bhi = max(bhi, __shfl_xor(bhi, r, 64));
        }
        if (lane == 0) {
            s_rng[0] = min(max(blo, 0), NB - 1);
            s_rng[1] = min(max(bhi, 0), NB - 1);
        }
    }
    __syncthreads();

    const int bblo = s_rng[0], bbhi = s_rng[1];

    // ---- round 1: block-union window minus round-0 range (disjoint) ----
    k0 = k1 = k2 = ~0ULL; d2f = finf();
    if (bblo < c_lo) {
        const int La = __builtin_amdgcn_readfirstlane(soffs[bblo]);
        SCAN_SPAN(La, S0);
    }
    if (bbhi > c_hi) {
        const int Rb = __builtin_amdgcn_readfirstlane(soffs[bbhi + 1]);
        SCAN_SPAN(S1, Rb);
    }
    s_k[wave][0][lane] = make_uint2((unsigned)k0, (unsigned)(k0 >> 32));
    s_k[wave][1][lane] = make_uint2((unsigned)k1, (unsigned)(k1 >> 32));
    s_k[wave][2][lane] = make_uint2((unsigned)k2, (unsigned)(k2 >> 32));
    __syncthreads();

    if (wave == 0) {
        unsigned long long K0, K1, K2;
        {
            uint2 a = s_m[0][lane], b = s_m[1][lane], c = s_m[2][lane];
            K0 = ((unsigned long long)a.y << 32) | a.x;
            K1 = ((unsigned long long)b.y << 32) | b.x;
            K2 = ((unsigned long long)c.y << 32) | c.x;
        }
        #pragma unroll
        for (int w = 0; w < 16; ++w)
            #pragma unroll
            for (int r = 0; r < 3; ++r) {
                uint2 u = s_k[w][r][lane];
                unsigned long long k = ((unsigned long long)u.y << 32) | u.x;
                insert3k(k, K0, K1, K2);
            }
        float b0 = key_d(K0), b1 = key_d(K1), b2 = key_d(K2);
        // FROZEN weights (R5): w = 1/(d+eps); w /= (w0+w1)+w2
        float w0 = __fdiv_rn(1.f, __fadd_rn(b0, EPS));
        float w1 = __fdiv_rn(1.f, __fadd_rn(b1, EPS));
        float w2 = __fdiv_rn(1.f, __fadd_rn(b2, EPS));
        float sum = __fadd_rn(__fadd_rn(w0, w1), w2);
        s_w[0][lane] = __fdiv_rn(w0, sum);
        s_w[1][lane] = __fdiv_rn(w1, sum);
        s_w[2][lane] = __fdiv_rn(w2, sum);
        s_j[0][lane] = (int)(unsigned)(K0 & 0xffffffffu);
        s_j[1][lane] = (int)(unsigned)(K1 & 0xffffffffu);
        s_j[2][lane] = (int)(unsigned)(K2 & 0xffffffffu);
        s_o[lane]    = orig;
    }
    __syncthreads();

    // interpolation: 16 threads/query, float4 loads/stores (C%64==0)
    const int tm = tid >> 4;
    const int qq = tid & 15;
    if (blockIdx.x * 64 + tm < M) {
        const int nv = C >> 6;
        const int row = s_o[tm];
        const float w0 = s_w[0][tm], w1 = s_w[1][tm], w2 = s_w[2][tm];
        const float4* f0 = (const float4*)(feat + (size_t)s_j[0][tm] * C) + qq * nv;
        const float4* f1 = (const float4*)(feat + (size_t)s_j[1][tm] * C) + qq * nv;
        const float4* f2 = (const float4*)(feat + (size_t)s_j[2][tm] * C) + qq * nv;
        float4* o = (float4*)(out + (size_t)row * C) + qq * nv;
        for (int r = 0; r < nv; ++r) {
            float4 a = f0[r], b = f1[r], c = f2[r];
            float4 v;
            v.x = w0 * a.x + w1 * b.x + w2 * c.x;
            v.y = w0 * a.y + w1 * b.y + w2 * c.y;
            v.z = w0 * a.z + w1 * b.z + w2 * c.z;
            v.w = w0 * a.w + w1 * b.w + w2 * c.w;
            o[r] = v;
        }
    }
}

// ---------------- dense fallback (validated R7 path) ----------------
#define NW 16
__global__ void knn_preproc(const float* __restrict__ sp, float4* __restrict__ sp4, int N) {
    int j = blockIdx.x * blockDim.x + threadIdx.x;
    if (j < N) {
        float x = sp[3 * j + 0], y = sp[3 * j + 1], z = sp[3 * j + 2];
        float s2 = __fadd_rn(__fadd_rn(__fmul_rn(x, x), __fmul_rn(y, y)), __fmul_rn(z, z));
        sp4[j] = make_float4(-2.f * x, -2.f * y, -2.f * z, s2);
    }
}
__device__ __forceinline__ void insert3_bl(float d, int j,
                                           float& d0, float& d1, float& d2,
                                           int& i0, int& i1, int& i2) {
    const bool c0 = d < d0, c1 = d < d1, c2 = d < d2;
    const float nd2 = c1 ? d1 : (c2 ? d : d2);
    const int   ni2 = c1 ? i1 : (c2 ? j : i2);
    const float nd1 = c0 ? d0 : (c1 ? d : d1);
    const int   ni1 = c0 ? i0 : (c1 ? j : i1);
    const float nd0 = c0 ? d : d0;
    const int   ni0 = c0 ? j : i0;
    d0 = nd0; d1 = nd1; d2 = nd2;
    i0 = ni0; i1 = ni1; i2 = ni2;
}
#define SCORE_INSERT(p, jv) do {                                          \
    float _a = fmaf((p).z, tz, fmaf((p).y, ty, __fmul_rn((p).x, tx)));    \
    float _d = __fadd_rn(__fadd_rn(t2, _a), (p).w);                       \
    if (__any(_d < d2))                                                   \
        insert3_bl(_d, (jv), d0, d1, d2, i0, i1, i2);                     \
} while (0)
__global__ __launch_bounds__(1024, 8) void knn_dense(
    const float4* __restrict__ sp4, const float* __restrict__ feat,
    const float* __restrict__ tp, float* __restrict__ out,
    int N, int M, int C) {
    __shared__ float s_d[NW][3][64];
    __shared__ int   s_i[NW][3][64];
    __shared__ float s_w[3][64];
    __shared__ int   s_j[3][64];
    const int tid  = threadIdx.x;
    const int lane = tid & 63;
    const int wave = __builtin_amdgcn_readfirstlane(tid >> 6);
    const int mbase = blockIdx.x * 64;
    const int m = mbase + lane;
    float tx = 0.f, ty = 0.f, tz = 0.f;
    if (m < M) { tx = tp[3 * m + 0]; ty = tp[3 * m + 1]; tz = tp[3 * m + 2]; }
    const float t2 = __fadd_rn(__fadd_rn(__fmul_rn(tx, tx), __fmul_rn(ty, ty)),
                               __fmul_rn(tz, tz));
    float d0 = FMAXV, d1 = FMAXV, d2 = FMAXV;
    int   i0 = 0,     i1 = 0,     i2 = 0;
    const int chunk = (N + NW - 1) / NW;
    const int jbeg = wave * chunk;
    const int jend = min(jbeg + chunk, N);
    int j = jbeg;
    for (; j + 8 <= jend; j += 8) {
        float4 p0 = sp4[j + 0], p1 = sp4[j + 1], p2 = sp4[j + 2], p3 = sp4[j + 3];
        float4 p4 = sp4[j + 4], p5 = sp4[j + 5], p6 = sp4[j + 6], p7 = sp4[j + 7];
        SCORE_INSERT(p0, j + 0); SCORE_INSERT(p1, j + 1);
        SCORE_INSERT(p2, j + 2); SCORE_INSERT(p3, j + 3);
        SCORE_INSERT(p4, j + 4); SCORE_INSERT(p5, j + 5);
        SCORE_INSERT(p6, j + 6); SCORE_INSERT(p7, j + 7);
    }
    for (; j < jend; ++j) { float4 p = sp4[j]; SCORE_INSERT(p, j); }
    s_d[wave][0][lane] = d0; s_d[wave][1][lane] = d1; s_d[wave][2][lane] = d2;
    s_i[wave][0][lane] = i0; s_i[wave][1][lane] = i1; s_i[wave][2][lane] = i2;
    __syncthreads();
    if (wave == 0) {
        float b0 = FMAXV, b1 = FMAXV, b2 = FMAXV;
        int   j0 = 0,     j1 = 0,     j2 = 0;
        #pragma unroll
        for (int w = 0; w < NW; ++w)
            #pragma unroll
            for (int k = 0; k < 3; ++k)
                insert3_bl(s_d[w][k][lane], s_i[w][k][lane], b0, b1, b2, j0, j1, j2);
        float w0 = __fdiv_rn(1.f, __fadd_rn(b0, EPS));
        float w1 = __fdiv_rn(1.f, __fadd_rn(b1, EPS));
        float w2 = __fdiv_rn(1.f, __fadd_rn(b2, EPS));
        float sum = __fadd_rn(__fadd_rn(w0, w1), w2);
        s_w[0][lane] = __fdiv_rn(w0, sum);
        s_w[1][lane] = __fdiv_rn(w1, sum);
        s_w[2][lane] = __fdiv_rn(w2, sum);
        s_j[0][lane] = j0; s_j[1][lane] = j1; s_j[2][lane] = j2;
    }
    __syncthreads();
    const int tm = tid >> 4;
    const int qq = tid & 15;
    const int gm = mbase + tm;
    if (gm < M) {
        const int nv = C >> 6;
        const float w0 = s_w[0][tm], w1 = s_w[1][tm], w2 = s_w[2][tm];
        const float4* f0 = (const float4*)(feat + (size_t)s_j[0][tm] * C) + qq * nv;
        const float4* f1 = (const float4*)(feat + (size_t)s_j[1][tm] * C) + qq * nv;
        const float4* f2 = (const float4*)(feat + (size_t)s_j[2][tm] * C) + qq * nv;
        float4* o = (float4*)(out + (size_t)gm * C) + qq * nv;
        for (int r = 0; r < nv; ++r) {
            float4 a = f0[r], b = f1[r], c = f2[r];
            float4 v;
            v.x = w0 * a.x + w1 * b.x + w2 * c.x;
            v.y = w0 * a.y + w1 * b.y + w2 * c.y;
            v.z = w0 * a.z + w1 * b.z + w2 * c.z;
            v.w = w0 * a.w + w1 * b.w + w2 * c.w;
            o[r] = v;
        }
    }
}

// ---------------- host ----------------
static inline size_t align256(size_t x) { return (x + 255) & ~(size_t)255; }

extern "C" void kernel_launch(void* const* d_in, const int* in_sizes, int n_in,
                              void* d_out, int out_size, void* d_ws, size_t ws_size,
                              hipStream_t stream) {
    const float* sp   = (const float*)d_in[0];  // source_points [N,3]
    const float* feat = (const float*)d_in[1];  // source_features [N,C]
    const float* tp   = (const float*)d_in[2];  // target_points [M,3]
    float* out = (float*)d_out;                 // [M,C] fp32

    const int N = in_sizes[0] / 3;
    const int C = in_sizes[1] / N;
    const int M = in_sizes[2] / 3;

    // ws layout (windowed path)
    size_t oScnt  = 0;                                   // NB ints (then cursor)
    size_t oQcnt  = oScnt + (size_t)NB * 4;              // NB ints
    size_t oSoffs = align256(oQcnt + (size_t)NB * 4);    // NB+1 ints
    size_t oQoffs = align256(oSoffs + (size_t)(NB + 1) * 4);
    size_t oSpts  = align256(oQoffs + (size_t)(NB + 1) * 4);  // N float4
    size_t oSidx  = align256(oSpts + (size_t)N * 16);         // N ints
    size_t oQpts  = align256(oSidx + (size_t)N * 4);          // M float4
    size_t need   = oQpts + (size_t)M * 16;

    if (ws_size >= need && (C & 63) == 0) {
        char* ws = (char*)d_ws;
        int*    scnt  = (int*)(ws + oScnt);
        int*    qcnt  = (int*)(ws + oQcnt);
        int*    soffs = (int*)(ws + oSoffs);
        int*    qoffs = (int*)(ws + oQoffs);
        float4* spts  = (float4*)(ws + oSpts);
        int*    sidxp = (int*)(ws + oSidx);
        float4* qpts  = (float4*)(ws + oQpts);

        hipMemsetAsync(scnt, 0, (size_t)2 * NB * 4, stream);
        int nmBlocks = (N + M + 255) / 256;
        k_hist2<<<nmBlocks, 256, 0, stream>>>(sp, N, tp, M, scnt, qcnt);
        k_scan2<<<2, NB, 0, stream>>>(scnt, soffs, qcnt, qoffs);
        k_scat2<<<nmBlocks, 256, 0, stream>>>(sp, N, tp, M, scnt, spts, sidxp, qcnt, qpts);
        k_knn_blk<<<(M + 63) / 64, 1024, 0, stream>>>(spts, sidxp, soffs, qpts, feat, out, M, C);
    } else {
        // dense fallback (validated R7)
        float4* sp4 = (float4*)d_ws;
        knn_preproc<<<(N + 255) / 256, 256, 0, stream>>>(sp, sp4, N);
        knn_dense<<<(M + 63) / 64, 1024, 0, stream>>>(sp4, feat, tp, out, N, M, C);
    }
}